// Round 11
// baseline (357.392 us; speedup 1.0000x reference)
//
#include <hip/hip_runtime.h>

// MultiHeadAttention: B=4, S=2048, E=1024, H=16, DK=64. fp32 in/out, bf16 MFMA internally.
//
// Pipeline (4 dispatches):
//   cvt_all:  x,Wq,Wk,Wv,Wo fp32 -> bf16 in one launch (Wq scaled by 1/sqrt(64)*log2(e))
//   gemm_qkv: Q,K = x@W^T -> (b*H+h, s, d); V = x@Wv^T -> (b*H+h, d, s) transposed
//   attn:     flash attention, NO-MAX softmax (exp2 domain), truncated-bf16 P.
//   gemm_out: out = ctx@Wo^T -> fp32
//
// R16 post-mortem: attn-mt4 + out-128^2 net zero (mt4 halved attn TLP; regime
// unchanged). 8 rounds of 2-barrier tweaks all land ~500 TF / MfmaUtil 20% -> the
// STRUCTURE's bytes-per-FLOP is the cap (24KB LDS-staged per 2.1 MFLOP at 128x256).
// R17: 256^2 tile, BK=64, 8 waves (512 thr) -- bytes/FLOP halved (64KB per 8.4 MF).
// Sync skeleton IDENTICAL to the 5x-proven loop (stage; sched_barrier; counted vmcnt;
// barrier; ds_read+MFMA; sched_barrier; barrier) -- parameter change only, no new
// barrier structure (R14 race class not reintroduced). LDS 128KB double-buffer,
// 1 block/CU, vmcnt(8), acc[8][4]=128 regs (~220 total < 256 at lb(512,2)).
// attn reverted to the 4x-proven mt=2 / 4-blocks-per-CU version.
//
// MFMA 16x16x32 bf16 layouts (learn_hip verified):
//   A: lane holds A[m=lane&15][k=(lane>>4)*8+j]   B: lane holds B[k=(lane>>4)*8+j][n=lane&15]
//   C/D: col=lane&15, row=(lane>>4)*4+reg
// LDS tiles chunk-major [kchunk][row][8 elems] -> b128 reads phase-complete (conflict floor).

typedef __bf16 bf16x8 __attribute__((ext_vector_type(8)));
typedef __bf16 bf16x4 __attribute__((ext_vector_type(4)));
typedef float floatx4 __attribute__((ext_vector_type(4)));
typedef unsigned int uint2v __attribute__((ext_vector_type(2)));

#define GLOAD_LDS16(gp, lp) __builtin_amdgcn_global_load_lds( \
    (const __attribute__((address_space(1))) unsigned int*)(gp), \
    (__attribute__((address_space(3))) unsigned int*)(lp), 16, 0, 0)

// ---------------------------------------------------------------- convert ----
__global__ __launch_bounds__(256) void cvt_all(const float4* __restrict__ x,
                                               const float4* __restrict__ Wq,
                                               const float4* __restrict__ Wk,
                                               const float4* __restrict__ Wv,
                                               const float4* __restrict__ Wo,
                                               bf16x4* __restrict__ xb,
                                               bf16x4* __restrict__ oq, bf16x4* __restrict__ ok,
                                               bf16x4* __restrict__ ov, bf16x4* __restrict__ oo,
                                               float qscale) {
    const int b = blockIdx.x;
    const float4* s;
    bf16x4* d;
    float scale = 1.0f;
    int i;
    if (b < 8192) {                 // x: 8192 blocks
        s = x; d = xb; i = b * 256 + threadIdx.x;
    } else {                        // weights: 4 x 1024 blocks (block-uniform branch)
        int g = (b - 8192) >> 10;   // 0:Wq 1:Wk 2:Wv 3:Wo
        s = (g == 0) ? Wq : (g == 1) ? Wk : (g == 2) ? Wv : Wo;
        d = (g == 0) ? oq : (g == 1) ? ok : (g == 2) ? ov : oo;
        if (g == 0) scale = qscale;
        i = ((b - 8192) & 1023) * 256 + threadIdx.x;
    }
    float4 v = s[i];
    bf16x4 o = { (__bf16)(v.x * scale), (__bf16)(v.y * scale),
                 (__bf16)(v.z * scale), (__bf16)(v.w * scale) };
    d[i] = o;
}

// ---------------------------------------------------------------- GEMM core --
// C[m][n] = sum_k A[m][k] * W[n][k], M=8192, N=1024, K=1024. 256x256 block tile,
// BK=64, 512 threads = 8 waves (wr=w>>2 in {0,1}, wc=w&3 in {0..3}); each wave
// computes 128x64 (mtg 8 x nt 4). LDS 128KB double-buffered; per dbuf 64KB:
//   A [8 kchunks][256 rows][8] at +0, B same at +32768 bytes.
// Per phase: stage(other dbuf, k+64) [8 gloads]; vmcnt(8) [prev stage landed, this
// stage's 8 stay in flight across the whole compute]; s_barrier; 24 ds_read_b128 +
// 64 MFMA; s_barrier.  [sync skeleton identical to the 5x-proven 2-barrier loop]

__device__ __forceinline__ void gemm_stage(const __bf16* __restrict__ A,
                                           const __bf16* __restrict__ W,
                                           char* dbuf,
                                           int bm, int bn, int k0, int w, int lane) {
    // A: 2048 cells (8 kchunks x 256 rows), 4 GLOADs/lane; B same.
#pragma unroll
    for (int j = 0; j < 4; ++j) {
        int base = j * 512 + w * 64;      // wave-uniform cell index
        int flat = base + lane;
        int kc = flat >> 8, r = flat & 255;
        GLOAD_LDS16(A + (size_t)(bm + r) * 1024 + k0 + kc * 8, dbuf + base * 16);
        GLOAD_LDS16(W + (size_t)(bn + r) * 1024 + k0 + kc * 8, dbuf + 32768 + base * 16);
    }
}

__device__ __forceinline__ void gemm_phase(const __bf16* __restrict__ A,
                                           const __bf16* __restrict__ W,
                                           const char* dr, char* ds,
                                           int bm, int bn, int ks,
                                           int w, int lane, int quad, int l15,
                                           int wr, int wc,
                                           floatx4 acc[8][4]) {
    // issue prefetch for the NEXT K-tile into the other dbuf (8 gload_lds)
    gemm_stage(A, W, ds, bm, bn, ks, w, lane);
    __builtin_amdgcn_sched_barrier(0);
    // wait for the PREVIOUS stage (this phase's read dbuf): 8 newest stay in flight
    asm volatile("s_waitcnt vmcnt(8)" ::: "memory");
    __builtin_amdgcn_s_barrier();          // all waves' portions of read-dbuf landed
    __builtin_amdgcn_sched_barrier(0);

#pragma unroll
    for (int ksub = 0; ksub < 2; ++ksub) {
        const int kc = ksub * 4 + quad;
        bf16x8 af[8], bf[4];
#pragma unroll
        for (int mtg = 0; mtg < 8; ++mtg)
            af[mtg] = *(const bf16x8*)(dr + (kc * 256 + wr * 128 + mtg * 16 + l15) * 16);
#pragma unroll
        for (int nt = 0; nt < 4; ++nt)
            bf[nt] = *(const bf16x8*)(dr + 32768 + (kc * 256 + wc * 64 + nt * 16 + l15) * 16);
#pragma unroll
        for (int mtg = 0; mtg < 8; ++mtg)
#pragma unroll
            for (int nt = 0; nt < 4; ++nt)
                acc[mtg][nt] = __builtin_amdgcn_mfma_f32_16x16x32_bf16(af[mtg], bf[nt],
                                                                       acc[mtg][nt], 0, 0, 0);
    }
    __builtin_amdgcn_sched_barrier(0);
    __builtin_amdgcn_s_barrier();          // reads of read-dbuf done (drained by MFMA lgkmcnt)
}

__device__ __forceinline__ void gemm_mainloop(const __bf16* __restrict__ A,
                                              const __bf16* __restrict__ W,
                                              char* SM,
                                              int bm, int bn, int tid,
                                              floatx4 acc[8][4]) {
    const int w = tid >> 6, lane = tid & 63;
    const int quad = lane >> 4, l15 = lane & 15;
    const int wr = w >> 2, wc = w & 3;
    char* d0 = SM;             // dbuf 0: A 32KB + B 32KB
    char* d1 = SM + 65536;     // dbuf 1
#pragma unroll
    for (int i = 0; i < 8; ++i)
#pragma unroll
        for (int j = 0; j < 4; ++j) acc[i][j] = (floatx4){0.f, 0.f, 0.f, 0.f};

    // prologue: stage K-tile 0 into dbuf 0
    gemm_stage(A, W, d0, bm, bn, 0, w, lane);

    // 8 double-iterations (16 K-tiles). Final phase stages k0=1024 (garbage, lands
    // ~1-2KB past the operand buffer into the adjacent mapped workspace buffer; never
    // consumed) so vmcnt(8) stays uniform; drained by the trailing __syncthreads.
    for (int k0 = 0; k0 < 1024; k0 += 128) {
        gemm_phase(A, W, d0, d1, bm, bn, k0 + 64, w, lane, quad, l15, wr, wc, acc);
        gemm_phase(A, W, d1, d0, bm, bn, k0 + 128, w, lane, quad, l15, wr, wc, acc);
    }
    __syncthreads();  // drains garbage prefetch + all waves done before epilogue scratch
}

// Fused QKV: grid (12, 32). blockIdx.x: sel = x>>2 (0:Q 1:K 2:V), bn = (x&3)*256;
// blockIdx.y = bm/256 (x-fastest dispatch -> 12 same-A-panel blocks concurrent).
__global__ __launch_bounds__(512, 2) void gemm_qkv(const __bf16* __restrict__ A,
                                                   const __bf16* __restrict__ Wqb,
                                                   const __bf16* __restrict__ Wkb,
                                                   const __bf16* __restrict__ Wvb,
                                                   __bf16* __restrict__ Qg,
                                                   __bf16* __restrict__ Kg,
                                                   __bf16* __restrict__ Vtg) {
    __shared__ alignas(16) char SM[131072];   // 128 KB (double-buffered)
    const int sel = blockIdx.x >> 2;                      // block-uniform
    const __bf16* W = (sel == 0) ? Wqb : (sel == 1) ? Wkb : Wvb;
    __bf16* ob = (sel == 0) ? Qg : (sel == 1) ? Kg : Vtg;
    const int bm = blockIdx.y * 256, bn = (blockIdx.x & 3) * 256;
    const int tid = threadIdx.x;
    const int w = tid >> 6, lane = tid & 63;
    const int quad = lane >> 4, l15 = lane & 15;
    const int wr = w >> 2, wc = w & 3;

    floatx4 acc[8][4];
    gemm_mainloop(A, W, SM, bm, bn, tid, acc);

    // bf16 epilogue via per-wave LDS transpose -> 8B stores
    float* tb = (float*)SM + w * 272;  // [16][17] per wave (8 waves x 1088B)
    const int rr = lane >> 2, c0 = (lane & 3) * 4;
#pragma unroll
    for (int mtg = 0; mtg < 8; ++mtg)
#pragma unroll
        for (int nt = 0; nt < 4; ++nt) {
            if (sel == 2) {
#pragma unroll
                for (int r = 0; r < 4; ++r) tb[l15 * 17 + quad * 4 + r] = acc[mtg][nt][r];
            } else {
#pragma unroll
                for (int r = 0; r < 4; ++r) tb[(quad * 4 + r) * 17 + l15] = acc[mtg][nt][r];
            }
            // wave-lockstep: DS pipe in-order within a wave
            float f0 = tb[rr * 17 + c0 + 0], f1 = tb[rr * 17 + c0 + 1];
            float f2 = tb[rr * 17 + c0 + 2], f3 = tb[rr * 17 + c0 + 3];
            bf16x4 pk = { (__bf16)f0, (__bf16)f1, (__bf16)f2, (__bf16)f3 };
            if (sel <= 1) {
                int m = bm + wr * 128 + mtg * 16 + rr;    // s-row
                int n0 = bn + wc * 64 + nt * 16 + c0;     // 4 consecutive d
                int bI = m >> 11, s = m & 2047, h = n0 >> 6, d0 = n0 & 63;
                *(bf16x4*)(ob + ((size_t)(bI * 16 + h) * 2048 + s) * 64 + d0) = pk;
            } else {
                int m0 = bm + wr * 128 + mtg * 16 + c0;   // 4 consecutive s
                int n = bn + wc * 64 + nt * 16 + rr;      // d-row
                int bI = m0 >> 11, s0 = m0 & 2047, h = n >> 6, d = n & 63;
                *(bf16x4*)(ob + ((size_t)(bI * 16 + h) * 64 + d) * 2048 + s0) = pk;
            }
        }
}

// Final projection: fp32 out at m*1024+n. grid (4, 32): bn = x*256, bm = y*256.
__global__ __launch_bounds__(512, 2) void gemm_out(const __bf16* __restrict__ A,
                                                   const __bf16* __restrict__ W,
                                                   float* __restrict__ of) {
    __shared__ alignas(16) char SM[131072];   // 128 KB (double-buffered)
    const int tid = threadIdx.x;
    const int lane = tid & 63, w = tid >> 6;
    const int quad = lane >> 4, l15 = lane & 15;
    const int wr = w >> 2, wc = w & 3;
    const int bm = blockIdx.y * 256, bn = blockIdx.x * 256;

    floatx4 acc[8][4];
    gemm_mainloop(A, W, SM, bm, bn, tid, acc);

#pragma unroll
    for (int mtg = 0; mtg < 8; ++mtg)
#pragma unroll
        for (int nt = 0; nt < 4; ++nt)
#pragma unroll
            for (int r = 0; r < 4; ++r) {
                int m = bm + wr * 128 + mtg * 16 + quad * 4 + r;
                int n = bn + wc * 64 + nt * 16 + l15;
                of[(size_t)m * 1024 + n] = acc[mtg][nt][r];
            }
}

// ---------------------------------------------------------------- attention --
// [R12/R15-proven version, 4x passed] grid 1024 (XCD-swizzled); block 256; lb(256,4).
// Wave w owns q rows [w*32, w*32+32). 64-key KV tiles, 32 phases. LDS 40KB -> 4
// blocks/CU: Ksm0/Ksm1 8KB (K dbuf), Vsm 8KB (single), Psm 16KB (4KB/wave).
// P per wave: [c4=16][row=32] cells of 8B; conflict-free write AND read.
// Phase t: barrier A (Vsm free); issue V(t), K(t+1); vmcnt(4) [K(t) landed]; barrier B;
// QK(t); exp/pack; P-write; vmcnt(2) [V(t) landed]; barrier C; P-read+PV(t).

__device__ __forceinline__ void attn_stage_K(const __bf16* __restrict__ Kg,
                                             __bf16* Ks, int bh, int kv0,
                                             int w, int lane) {
#pragma unroll
    for (int j = 0; j < 2; ++j) {
        int base = j * 256 + w * 64;      // wave-uniform cell base
        int flat = base + lane;
        int c = flat >> 6, r = flat & 63;
        GLOAD_LDS16(Kg + ((size_t)bh * 2048 + kv0 + r) * 64 + c * 8, (char*)Ks + base * 16);
    }
}

__device__ __forceinline__ void attn_stage_V(const __bf16* __restrict__ Vtg,
                                             __bf16* Vs, int bh, int kv0,
                                             int w, int lane) {
#pragma unroll
    for (int j = 0; j < 2; ++j) {
        int base = j * 256 + w * 64;
        int flat = base + lane;
        int c = flat >> 6, r = flat & 63;
        GLOAD_LDS16(Vtg + ((size_t)bh * 64 + r) * 2048 + kv0 + c * 8, (char*)Vs + base * 16);
    }
}

__device__ __forceinline__ void attn_phase(const __bf16* __restrict__ Kg,
                                           const __bf16* __restrict__ Vtg,
                                           const __bf16* Ksr, __bf16* Kss,
                                           __bf16* Vsm,
                                           char* Pw, const bf16x8 qf[2][2],
                                           int bh, int kv_cur, int kv_next,
                                           int w, int lane, int quad, int l15,
                                           float l_p[2], floatx4 o[2][4]) {
    __builtin_amdgcn_s_barrier();          // A: prev PV done -> Vsm overwritable
    __builtin_amdgcn_sched_barrier(0);
    attn_stage_V(Vtg, Vsm, bh, kv_cur * 64, w, lane);   // 2 gloads (oldest of this phase)
    attn_stage_K(Kg, Kss, bh, kv_next * 64, w, lane);   // 2 gloads (newest)
    __builtin_amdgcn_sched_barrier(0);
    // outstanding: [K(t) 2] + [V(t) 2, K(t+1) 2] -> wait K(t), keep 4 in flight
    asm volatile("s_waitcnt vmcnt(4)" ::: "memory");
    __builtin_amdgcn_s_barrier();          // B: K(t) visible to all waves
    __builtin_amdgcn_sched_barrier(0);

    // scores, SWAPPED: sa[mt][nt] = mfma(K_frag, Q_frag) = C[key][qrow]
    floatx4 sa[2][4];
#pragma unroll
    for (int mt = 0; mt < 2; ++mt)
#pragma unroll
        for (int nt = 0; nt < 4; ++nt) sa[mt][nt] = (floatx4){0.f, 0.f, 0.f, 0.f};
#pragma unroll
    for (int nt = 0; nt < 4; ++nt) {
        bf16x8 kb0 = *(const bf16x8*)(Ksr + (quad * 64 + nt * 16 + l15) * 8);
        bf16x8 kb1 = *(const bf16x8*)(Ksr + ((4 + quad) * 64 + nt * 16 + l15) * 8);
#pragma unroll
        for (int mt = 0; mt < 2; ++mt) {
            sa[mt][nt] = __builtin_amdgcn_mfma_f32_16x16x32_bf16(kb0, qf[mt][0],
                                                                sa[mt][nt], 0, 0, 0);
            sa[mt][nt] = __builtin_amdgcn_mfma_f32_16x16x32_bf16(kb1, qf[mt][1],
                                                                sa[mt][nt], 0, 0, 0);
        }
    }

    // p = exp2(s); lane holds qrow mt*16+l15, keys nt*16+quad*4+{0..3} (consecutive)
    // -> pack 4 bf16 via 2x v_perm (bit-identical truncation), ONE 8B cell write.
#pragma unroll
    for (int mt = 0; mt < 2; ++mt)
#pragma unroll
        for (int nt = 0; nt < 4; ++nt) {
            float p0 = __builtin_amdgcn_exp2f(sa[mt][nt][0]);
            float p1 = __builtin_amdgcn_exp2f(sa[mt][nt][1]);
            float p2 = __builtin_amdgcn_exp2f(sa[mt][nt][2]);
            float p3 = __builtin_amdgcn_exp2f(sa[mt][nt][3]);
            l_p[mt] += (p0 + p1) + (p2 + p3);
            unsigned u0 = __builtin_bit_cast(unsigned, p0);
            unsigned u1 = __builtin_bit_cast(unsigned, p1);
            unsigned u2 = __builtin_bit_cast(unsigned, p2);
            unsigned u3 = __builtin_bit_cast(unsigned, p3);
            uint2v pk;
            pk.x = __builtin_amdgcn_perm(u1, u0, 0x07060302);  // {u0.hi16, u1.hi16}
            pk.y = __builtin_amdgcn_perm(u3, u2, 0x07060302);  // {u2.hi16, u3.hi16}
            *(uint2v*)(Pw + ((nt * 4 + quad) * 32 + mt * 16 + l15) * 8) = pk;
        }

    __builtin_amdgcn_sched_barrier(0);
    // outstanding: [V(t) 2, K(t+1) 2] -> wait V(t), keep K(t+1) in flight
    asm volatile("s_waitcnt vmcnt(2)" ::: "memory");
    __builtin_amdgcn_s_barrier();          // C: all waves' V(t) parts landed
    __builtin_amdgcn_sched_barrier(0);

    // PV: P (wave-private, 2x b64 per fragment) @ V  (16 MFMAs)
#pragma unroll
    for (int kk = 0; kk < 2; ++kk) {
        const int c4a = (kk * 4 + quad) * 2;
        bf16x4 lo0 = *(const bf16x4*)(Pw + (c4a * 32 + l15) * 8);
        bf16x4 hi0 = *(const bf16x4*)(Pw + ((c4a + 1) * 32 + l15) * 8);
        bf16x4 lo1 = *(const bf16x4*)(Pw + (c4a * 32 + 16 + l15) * 8);
        bf16x4 hi1 = *(const bf16x4*)(Pw + ((c4a + 1) * 32 + 16 + l15) * 8);
        bf16x8 pa0 = __builtin_shufflevector(lo0, hi0, 0, 1, 2, 3, 4, 5, 6, 7);
        bf16x8 pa1 = __builtin_shufflevector(lo1, hi1, 0, 1, 2, 3, 4, 5, 6, 7);
#pragma unroll
        for (int dt = 0; dt < 4; ++dt) {
            bf16x8 vb = *(const bf16x8*)(Vsm + ((kk * 4 + quad) * 64 + dt * 16 + l15) * 8);
            o[0][dt] = __builtin_amdgcn_mfma_f32_16x16x32_bf16(pa0, vb, o[0][dt], 0, 0, 0);
            o[1][dt] = __builtin_amdgcn_mfma_f32_16x16x32_bf16(pa1, vb, o[1][dt], 0, 0, 0);
        }
    }
    __builtin_amdgcn_sched_barrier(0);
}

__global__ __launch_bounds__(256, 4) void attn_kernel(const __bf16* __restrict__ Qg,
                                                      const __bf16* __restrict__ Kg,
                                                      const __bf16* __restrict__ Vtg,
                                                      __bf16* __restrict__ ctxg) {
    __shared__ alignas(16) __bf16 Ksm0[4096];  // 8KB (epilogue scratch after loop)
    __shared__ alignas(16) __bf16 Ksm1[4096];  // 8KB
    __shared__ alignas(16) __bf16 Vsm[4096];   // 8KB (single-buffered)
    __shared__ alignas(16) __bf16 Psm[8192];   // 16KB: P, 4KB per wave
    const int tid = threadIdx.x;
    const int w = tid >> 6, lane = tid & 63;
    const int quad = lane >> 4, l15 = lane & 15;

    // XCD-aware bijective swizzle (1024 = 8 XCDs x 128): XCD x owns bh in [8x, 8x+8)
    const int orig = blockIdx.x;
    const int wg = (orig & 7) * 128 + (orig >> 3);
    const int qbase = (wg & 15) * 128;
    const int bh = wg >> 4;

    char* Pw = (char*)Psm + w * 4096;

    // Q fragments: 32 q rows per wave, 2 m-tiles
    bf16x8 qf[2][2];
#pragma unroll
    for (int mt = 0; mt < 2; ++mt) {
        const __bf16* qrow = Qg + ((size_t)bh * 2048 + qbase + w * 32 + mt * 16 + l15) * 64;
        qf[mt][0] = *(const bf16x8*)(qrow + quad * 8);
        qf[mt][1] = *(const bf16x8*)(qrow + 32 + quad * 8);
    }

    float l_p[2] = {0.f, 0.f};   // per-lane partial row-sum for qrow mt*16+l15
    floatx4 o[2][4];
#pragma unroll
    for (int mt = 0; mt < 2; ++mt)
#pragma unroll
        for (int dt = 0; dt < 4; ++dt) o[mt][dt] = (floatx4){0.f, 0.f, 0.f, 0.f};

    // prologue: stage K tile 0 into buffer 0
    attn_stage_K(Kg, Ksm0, bh, 0, w, lane);

    // 16 double-phases, static K-buffer selection. Last phase stages K(32): garbage
    // but in-workspace (bh=63 spill lands in Vtg). Trailing __syncthreads drains it.
    for (int kv = 0; kv < 32; kv += 2) {
        attn_phase(Kg, Vtg, Ksm0, Ksm1, Vsm, Pw, qf, bh, kv, kv + 1,
                   w, lane, quad, l15, l_p, o);
        attn_phase(Kg, Vtg, Ksm1, Ksm0, Vsm, Pw, qf, bh, kv + 1, kv + 2,
                   w, lane, quad, l15, l_p, o);
    }

    __syncthreads();  // drains garbage prefetch; all waves done before epilogue scratch

    // l reduction: quads hold disjoint key subsets of qrow l15
    float invr[2][4];
    {
        float inv[2];
#pragma unroll
        for (int mt = 0; mt < 2; ++mt) {
            float t = l_p[mt];
            t += __shfl_xor(t, 16);
            t += __shfl_xor(t, 32);
            inv[mt] = 1.f / t;
        }
        // o[mt][dt][r] belongs to qrow mt*16 + quad*4 + r; its inv lives at lane quad*4+r
#pragma unroll
        for (int mt = 0; mt < 2; ++mt)
#pragma unroll
            for (int r = 0; r < 4; ++r)
                invr[mt][r] = __shfl(inv[mt], quad * 4 + r);
    }

    float* tb = (float*)Ksm0 + w * 272;  // [16][17] per wave (4x272 floats fits 8KB)
    const int bI = bh >> 4, h = bh & 15;
    const int rr = lane >> 2, c0 = (lane & 3) * 4;
#pragma unroll
    for (int mt = 0; mt < 2; ++mt)
#pragma unroll
        for (int dt = 0; dt < 4; ++dt) {
#pragma unroll
            for (int r = 0; r < 4; ++r)
                tb[(quad * 4 + r) * 17 + l15] = o[mt][dt][r] * invr[mt][r];
            // wave-lockstep: DS pipe in-order within a wave
            float f0 = tb[rr * 17 + c0 + 0], f1 = tb[rr * 17 + c0 + 1];
            float f2 = tb[rr * 17 + c0 + 2], f3 = tb[rr * 17 + c0 + 3];
            bf16x4 pk = { (__bf16)f0, (__bf16)f1, (__bf16)f2, (__bf16)f3 };
            *(bf16x4*)(ctxg + ((size_t)(bI * 2048 + qbase + w * 32 + mt * 16 + rr)) * 1024
                       + h * 64 + dt * 16 + c0) = pk;
        }
}

// ---------------------------------------------------------------- launch -----
extern "C" void kernel_launch(void* const* d_in, const int* in_sizes, int n_in,
                              void* d_out, int out_size, void* d_ws, size_t ws_size,
                              hipStream_t stream) {
    const float* x  = (const float*)d_in[0];
    const float* Wq = (const float*)d_in[1];
    const float* Wk = (const float*)d_in[2];
    const float* Wv = (const float*)d_in[3];
    const float* Wo = (const float*)d_in[4];
    float* out = (float*)d_out;
    char* ws = (char*)d_ws;

    // workspace map (72 MB): ctx aliases xb (x dead after QKV GEMMs)
    __bf16* xb  = (__bf16*)(ws);                    // 16 MB
    __bf16* wqb = (__bf16*)(ws + (16u << 20));      // 2 MB each
    __bf16* wkb = (__bf16*)(ws + (18u << 20));
    __bf16* wvb = (__bf16*)(ws + (20u << 20));
    __bf16* wob = (__bf16*)(ws + (22u << 20));
    __bf16* Qg  = (__bf16*)(ws + (24u << 20));      // 16 MB each
    __bf16* Kg  = (__bf16*)(ws + (40u << 20));
    __bf16* Vtg = (__bf16*)(ws + (56u << 20));
    __bf16* ctx = xb;

    // 1/sqrt(64) * log2(e): scores land in exp2 domain
    const float qscale = 0.18033688011112042f;

    cvt_all<<<12288, 256, 0, stream>>>((const float4*)x, (const float4*)Wq,
                                       (const float4*)Wk, (const float4*)Wv,
                                       (const float4*)Wo, (bf16x4*)xb,
                                       (bf16x4*)wqb, (bf16x4*)wkb,
                                       (bf16x4*)wvb, (bf16x4*)wob, qscale);

    gemm_qkv<<<dim3(12, 32), 512, 0, stream>>>(xb, wqb, wkb, wvb, Qg, Kg, Vtg);

    attn_kernel<<<1024, 256, 0, stream>>>(Qg, Kg, Vtg, ctx);

    gemm_out<<<dim3(4, 32), 512, 0, stream>>>(ctx, wob, out);
}